// Round 4
// baseline (664.685 us; speedup 1.0000x reference)
//
#include <hip/hip_runtime.h>
#include <hip/hip_fp16.h>
#include <stdint.h>

#define BB 16
#define NN 1620
#define DD 64
#define CC 128
#define KK 32
#define EPSV 1e-5f
#define PAIRS (BB*NN)            // 25920
#define ROWS  (PAIRS*KK)         // 829440
#define TILES (PAIRS/2)          // 12960 tiles of 64 rows
#define TPB_TILES 8
#define GRID_MM (TILES/TPB_TILES) // 1620
#define NCHUNK 26                // ceil(1620/64)

typedef _Float16 half8 __attribute__((ext_vector_type(8)));
typedef float f32x4 __attribute__((ext_vector_type(4)));

__device__ __forceinline__ float relu_(float v){ return v > 0.f ? v : 0.f; }

union H2U { __half2 h; unsigned u; };

// ---------------- x (B,D,N) fp32 -> feats (B,N,D) fp16 ----------------
__global__ void __launch_bounds__(256) k_prep_feats(const float* __restrict__ x,
                                                    __half* __restrict__ feats) {
    __shared__ float t[64*65];
    int b = blockIdx.y;
    int n0 = blockIdx.x * 64;
    int tid = threadIdx.x;
#pragma unroll
    for (int i = 0; i < 16; ++i) {
        int idx = i*256 + tid;
        int d = idx >> 6, nl = idx & 63;
        int n = n0 + nl;
        float v = 0.f;
        if (n < NN) v = x[((size_t)b*DD + d)*NN + n];
        t[d*65 + nl] = v;
    }
    __syncthreads();
#pragma unroll
    for (int i = 0; i < 8; ++i) {
        int idx = i*256 + tid;            // 64 nl x 32 d-pairs
        int nl = idx >> 5, dp = idx & 31;
        int n = n0 + nl;
        if (n < NN) {
            __half2 h = __floats2half2_rn(t[(dp*2)*65 + nl], t[(dp*2+1)*65 + nl]);
            *(__half2*)(feats + ((size_t)b*NN + n)*DD + dp*2) = h;
        }
    }
}

// ---------------- w fp32 -> fp16 (same [o][c] layout) ----------------
__global__ void k_convert_w(const float* __restrict__ w1, const float* __restrict__ w2,
                            __half* __restrict__ w1h, __half* __restrict__ w2h) {
    int i = blockIdx.x*256 + threadIdx.x;   // 64 blocks * 256 = 16384
    w1h[i] = __float2half(w1[i]);
    w2h[i] = __float2half(w2[i]);
}

// ---------------- KNN: one wave per query, radix-histogram rank selection ----------------
__global__ void __launch_bounds__(64) k_knn(const float* __restrict__ coords,
                                            int* __restrict__ idx_out) {
#pragma clang fp contract(off)
    __shared__ int hist[256];
    __shared__ unsigned bcast[2];   // [0]=bucket, [1]=count below bucket
    int p = blockIdx.x;
    int b = p / NN, n = p - b*NN;
    int lane = threadIdx.x;
    const float* cb = coords + (size_t)b*NN*3;
    float qx = cb[n*3+0], qy = cb[n*3+1], qz = cb[n*3+2];
    float sqn = (qx*qx + qy*qy) + qz*qz;

    unsigned key[NCHUNK];
#pragma unroll
    for (int i = 0; i < NCHUNK; ++i) {
        int m = lane + i*64;
        unsigned u = 0xFFFFFFFFu;
        if (m < NN) {
            float cx = cb[m*3+0], cy = cb[m*3+1], cz = cb[m*3+2];
            float sqm = (cx*cx + cy*cy) + cz*cz;
            float dot = (qx*cx + qy*cy) + qz*cz;
            float d = (sqn + sqm) - 2.0f*dot;
            unsigned t = __float_as_uint(d);
            u = (t & 0x80000000u) ? ~t : (t | 0x80000000u);
        }
        key[i] = u;
    }

    // ---- pass A: histogram on key[31:24] ----
#pragma unroll
    for (int i = 0; i < 4; ++i) hist[lane + i*64] = 0;
    __syncthreads();
#pragma unroll
    for (int i = 0; i < NCHUNK; ++i) {
        int m = lane + i*64;
        if (m < NN) atomicAdd(&hist[key[i] >> 24], 1);
    }
    __syncthreads();
    {
        int v0 = hist[lane*4+0], v1 = hist[lane*4+1], v2 = hist[lane*4+2], v3 = hist[lane*4+3];
        int c1 = v0+v1, c2 = c1+v2, c3 = c2+v3;
        int inc = c3;
#pragma unroll
        for (int off = 1; off < 64; off <<= 1) {
            int t = __shfl_up(inc, off);
            if (lane >= off) inc += t;
        }
        int base = inc - c3;
        if (base < KK) {
            int u0 = base+v0, u1 = base+c1, u2 = base+c2, u3 = base+c3;
            if      (u0 >= KK) { bcast[0] = lane*4+0; bcast[1] = base; }
            else if (u1 >= KK) { bcast[0] = lane*4+1; bcast[1] = u0; }
            else if (u2 >= KK) { bcast[0] = lane*4+2; bcast[1] = u1; }
            else if (u3 >= KK) { bcast[0] = lane*4+3; bcast[1] = u2; }
        }
    }
    __syncthreads();
    unsigned BA = bcast[0];
    int rA = KK - (int)bcast[1];
    __syncthreads();

    // ---- pass B: histogram on key[23:16] within bucket BA ----
#pragma unroll
    for (int i = 0; i < 4; ++i) hist[lane + i*64] = 0;
    __syncthreads();
#pragma unroll
    for (int i = 0; i < NCHUNK; ++i) {
        int m = lane + i*64;
        if (m < NN && (key[i] >> 24) == BA) atomicAdd(&hist[(key[i] >> 16) & 255], 1);
    }
    __syncthreads();
    {
        int v0 = hist[lane*4+0], v1 = hist[lane*4+1], v2 = hist[lane*4+2], v3 = hist[lane*4+3];
        int c1 = v0+v1, c2 = c1+v2, c3 = c2+v3;
        int inc = c3;
#pragma unroll
        for (int off = 1; off < 64; off <<= 1) {
            int t = __shfl_up(inc, off);
            if (lane >= off) inc += t;
        }
        int base = inc - c3;
        if (base < rA) {
            int u0 = base+v0, u1 = base+c1, u2 = base+c2, u3 = base+c3;
            if      (u0 >= rA) { bcast[0] = lane*4+0; bcast[1] = base; }
            else if (u1 >= rA) { bcast[0] = lane*4+1; bcast[1] = u0; }
            else if (u2 >= rA) { bcast[0] = lane*4+2; bcast[1] = u1; }
            else if (u3 >= rA) { bcast[0] = lane*4+3; bcast[1] = u2; }
        }
    }
    __syncthreads();
    unsigned prefix16 = (BA << 8) | bcast[0];
    int r = rA - (int)bcast[1];

    // ---- extract exact 32nd (key, m) pair ----
    unsigned long long fl = 0;
    for (int round = 0; round < r; ++round) {
        unsigned long long best = ~0ull;
#pragma unroll
        for (int i = 0; i < NCHUNK; ++i) {
            if ((key[i] >> 16) == prefix16) {
                unsigned long long v = ((unsigned long long)key[i] << 32) | (unsigned)(lane + i*64);
                if (v > fl && v < best) best = v;
            }
        }
#pragma unroll
        for (int off = 32; off; off >>= 1) {
            unsigned long long o = __shfl_xor(best, off, 64);
            if (o < best) best = o;
        }
        fl = best;
    }
    unsigned kstar = (unsigned)(fl >> 32);
    unsigned mstar = (unsigned)fl;

    int cnt = 0;
    unsigned long long mylow = (1ull << lane) - 1ull;
#pragma unroll
    for (int i = 0; i < NCHUNK; ++i) {
        unsigned m = lane + i*64;
        bool sel = (key[i] < kstar) || (key[i] == kstar && m <= mstar);
        unsigned long long bal = __ballot(sel);
        if (sel) {
            int pos = cnt + __popcll(bal & mylow);
            idx_out[p*KK + pos] = (int)m;
        }
        cnt += __popcll(bal);
    }
}

// ============ shared staging helpers (coalesced gather) ============
// Fill per-block row/center base tables for all TPB_TILES tiles.
__device__ __forceinline__ void fill_bases(const int* __restrict__ knn_idx,
                                           int blk, int tid, int* rowb, int* ctrb) {
#pragma unroll
    for (int e = tid; e < TPB_TILES*64; e += 256) {
        int tile = blk*TPB_TILES + (e >> 6);
        int rr = e & 63;
        int p = tile*2 + (rr >> 5);
        int nb = knn_idx[p*KK + (rr & 31)];
        int b = p / NN;
        rowb[e] = (b*NN + nb)*DD;
        ctrb[e] = p*DD;
    }
}

// Prefetch gather chunks for tile tloc into regs.
// Thread handles fixed kc = tid&15, rows it*16 + (tid>>4).
// kc<8: A = neighbor chunk (row contiguous across 8 lanes). kc>=8: A = center chunk.
__device__ __forceinline__ void stage_load(const __half* __restrict__ feats,
                                           const int* rowb, const int* ctrb,
                                           int tloc, int tid, uint4* A) {
    int kc = tid & 15;
#pragma unroll
    for (int it = 0; it < 4; ++it) {
        int row = it*16 + (tid >> 4);
        int e = tloc*64 + row;
        int ra = (kc < 8) ? (rowb[e] + kc*8) : (ctrb[e] + (kc-8)*8);
        A[it] = *(const uint4*)(feats + ra);
    }
}

// Write staged regs to LDS in MFMA chunk order; kc<8 lanes subtract center
// (center row loaded coalesced here, 1 distinct 128B row per wave instr).
__device__ __forceinline__ void stage_write(const __half* __restrict__ feats,
                                            const int* ctrb, int tloc, int tid,
                                            const uint4* A, __half* nf) {
    int kc = tid & 15;
#pragma unroll
    for (int it = 0; it < 4; ++it) {
        int row = it*16 + (tid >> 4);
        int e = tloc*64 + row;
        union { uint4 u; __half2 h[4]; } a, b, rr;
        a.u = A[it];
        if (kc < 8) {
            b.u = *(const uint4*)(feats + ctrb[e] + kc*8);
#pragma unroll
            for (int j = 0; j < 4; ++j) rr.h[j] = __hsub2(a.h[j], b.h[j]);
        } else {
            rr.u = a.u;
        }
        int C = (row >> 4)*256 + kc*16 + (row & 15);
        *(uint4*)(nf + C*8) = rr.u;
    }
}

// ---------------- pass 1: mm1 (MFMA) + stats1 ----------------
__global__ void __launch_bounds__(256, 4) k_mm1_mfma(const __half* __restrict__ feats,
                                                     const int* __restrict__ knn_idx,
                                                     const __half* __restrict__ w1h,
                                                     float* __restrict__ gsum,
                                                     float* __restrict__ gsumsq) {
    __shared__ __align__(16) __half nf[8192];          // 16 KB
    __shared__ int rowb[TPB_TILES*64];
    __shared__ int ctrb[TPB_TILES*64];
    int tid = threadIdx.x;
    int lane = tid & 63, wid = tid >> 6;
    int m = lane & 15, q = lane >> 4;

    fill_bases(knn_idx, blockIdx.x, tid, rowb, ctrb);

    half8 w1f[2][4];
#pragma unroll
    for (int ob = 0; ob < 2; ++ob)
#pragma unroll
        for (int t = 0; t < 4; ++t)
            w1f[ob][t] = *(const half8*)(w1h + (wid*32 + ob*16 + m)*CC + t*32 + q*8);

    f32x4 zero4 = {0.f, 0.f, 0.f, 0.f};
    f32x4 ssum[2] = {zero4, zero4}, ssq[2] = {zero4, zero4};

    __syncthreads();
    uint4 pf[4];
    stage_load(feats, rowb, ctrb, 0, tid, pf);

    for (int it = 0; it < TPB_TILES; ++it) {
        stage_write(feats, ctrb, it, tid, pf, nf);
        __syncthreads();
        if (it + 1 < TPB_TILES) stage_load(feats, rowb, ctrb, it + 1, tid, pf);

        f32x4 acc[2][4];
#pragma unroll
        for (int ob = 0; ob < 2; ++ob)
#pragma unroll
            for (int rbk = 0; rbk < 4; ++rbk) acc[ob][rbk] = zero4;

#pragma unroll
        for (int t = 0; t < 4; ++t)
#pragma unroll
            for (int rbk = 0; rbk < 4; ++rbk) {
                half8 bfr = *(const half8*)(nf + ((rbk*4 + t)*64 + lane)*8);
                acc[0][rbk] = __builtin_amdgcn_mfma_f32_16x16x32_f16(w1f[0][t], bfr, acc[0][rbk], 0, 0, 0);
                acc[1][rbk] = __builtin_amdgcn_mfma_f32_16x16x32_f16(w1f[1][t], bfr, acc[1][rbk], 0, 0, 0);
            }
#pragma unroll
        for (int ob = 0; ob < 2; ++ob)
#pragma unroll
            for (int rbk = 0; rbk < 4; ++rbk) {
                ssum[ob] += acc[ob][rbk];
                ssq[ob]  += acc[ob][rbk]*acc[ob][rbk];
            }
        __syncthreads();
    }
#pragma unroll
    for (int ob = 0; ob < 2; ++ob)
#pragma unroll
        for (int c = 0; c < 4; ++c) {
            float v = ssum[ob][c], v2 = ssq[ob][c];
#pragma unroll
            for (int off = 1; off < 16; off <<= 1) {
                v  += __shfl_xor(v,  off);
                v2 += __shfl_xor(v2, off);
            }
            if (m == 0) {
                int o = wid*32 + ob*16 + q*4 + c;
                atomicAdd(&gsum[o], v);
                atomicAdd(&gsumsq[o], v2);
            }
        }
}

// ---------------- finalize bn params ----------------
__global__ void k_finalize(const float* __restrict__ gsum, const float* __restrict__ gsumsq,
                           const float* __restrict__ g, const float* __restrict__ bb,
                           float* __restrict__ ab) {
    int o = threadIdx.x;
    float cnt = (float)ROWS;
    float mean = gsum[o] / cnt;
    float var = gsumsq[o] / cnt - mean*mean;
    float a = g[o] * rsqrtf(var + EPSV);
    ab[o] = a;
    ab[CC + o] = bb[o] - mean*a;
}

// ---------------- pass 2: mm1 + bn1relu + mm2 + stats2 + per-pair max/min ----------------
__global__ void __launch_bounds__(256, 3) k_fused_mfma(const __half* __restrict__ feats,
                                                       const int* __restrict__ knn_idx,
                                                       const __half* __restrict__ w1h,
                                                       const __half* __restrict__ w2h,
                                                       const float* __restrict__ ab1,
                                                       float* __restrict__ gsum2,
                                                       float* __restrict__ gsumsq2,
                                                       float* __restrict__ wsmax,
                                                       float* __restrict__ wsmin) {
    __shared__ __align__(16) __half nf[8192];     // 16 KB, chunk order
    __shared__ __align__(16) __half y1s[8192];    // 16 KB, same chunk order
    __shared__ int rowb[TPB_TILES*64];
    __shared__ int ctrb[TPB_TILES*64];
    int tid = threadIdx.x;
    int lane = tid & 63, wid = tid >> 6;
    int m = lane & 15, q = lane >> 4;

    fill_bases(knn_idx, blockIdx.x, tid, rowb, ctrb);

    half8 w1f[2][4], w2f[2][4];
#pragma unroll
    for (int ob = 0; ob < 2; ++ob)
#pragma unroll
        for (int t = 0; t < 4; ++t) {
            int o = wid*32 + ob*16 + m;
            w1f[ob][t] = *(const half8*)(w1h + o*CC + t*32 + q*8);
            w2f[ob][t] = *(const half8*)(w2h + o*CC + t*32 + q*8);
        }
    f32x4 a1v[2], c1v[2];
#pragma unroll
    for (int ob = 0; ob < 2; ++ob) {
        a1v[ob] = *(const f32x4*)(ab1 + wid*32 + ob*16 + q*4);
        c1v[ob] = *(const f32x4*)(ab1 + CC + wid*32 + ob*16 + q*4);
    }
    f32x4 zero4 = {0.f, 0.f, 0.f, 0.f};
    f32x4 ssum[2] = {zero4, zero4}, ssq[2] = {zero4, zero4};

    __syncthreads();
    uint4 pf[4];
    stage_load(feats, rowb, ctrb, 0, tid, pf);

    for (int it = 0; it < TPB_TILES; ++it) {
        int tile = blockIdx.x * TPB_TILES + it;
        stage_write(feats, ctrb, it, tid, pf, nf);
        __syncthreads();                               // B1
        if (it + 1 < TPB_TILES) stage_load(feats, rowb, ctrb, it + 1, tid, pf);

        f32x4 acc[2][4];
#pragma unroll
        for (int ob = 0; ob < 2; ++ob)
#pragma unroll
            for (int rbk = 0; rbk < 4; ++rbk) acc[ob][rbk] = zero4;

        // mm1: z1^T = w1 . nf^T
#pragma unroll
        for (int t = 0; t < 4; ++t)
#pragma unroll
            for (int rbk = 0; rbk < 4; ++rbk) {
                half8 bfr = *(const half8*)(nf + ((rbk*4 + t)*64 + lane)*8);
                acc[0][rbk] = __builtin_amdgcn_mfma_f32_16x16x32_f16(w1f[0][t], bfr, acc[0][rbk], 0, 0, 0);
                acc[1][rbk] = __builtin_amdgcn_mfma_f32_16x16x32_f16(w1f[1][t], bfr, acc[1][rbk], 0, 0, 0);
            }
        // bn1 + relu, write y1 in nf-style chunk order
#pragma unroll
        for (int ob = 0; ob < 2; ++ob)
#pragma unroll
            for (int rbk = 0; rbk < 4; ++rbk) {
                f32x4 z = acc[ob][rbk];
                float y0 = relu_(fmaf(a1v[ob][0], z[0], c1v[ob][0]));
                float y1 = relu_(fmaf(a1v[ob][1], z[1], c1v[ob][1]));
                float y2 = relu_(fmaf(a1v[ob][2], z[2], c1v[ob][2]));
                float y3 = relu_(fmaf(a1v[ob][3], z[3], c1v[ob][3]));
                H2U p0, p1;
                p0.h = __floats2half2_rn(y0, y1);
                p1.h = __floats2half2_rn(y2, y3);
                int kc = wid*4 + ob*2 + (q >> 1);       // channel-chunk index
                int C = rbk*256 + kc*16 + m;            // row = rbk*16+m
                uint2 v; v.x = p0.u; v.y = p1.u;
                *(uint2*)(y1s + C*8 + (q & 1)*4) = v;
            }
        __syncthreads();                               // B2

        // mm2: z2^T = w2 . y1^T  (reads identical in form to mm1)
#pragma unroll
        for (int ob = 0; ob < 2; ++ob)
#pragma unroll
            for (int rbk = 0; rbk < 4; ++rbk) acc[ob][rbk] = zero4;
#pragma unroll
        for (int t = 0; t < 4; ++t)
#pragma unroll
            for (int rbk = 0; rbk < 4; ++rbk) {
                half8 bfr = *(const half8*)(y1s + ((rbk*4 + t)*64 + lane)*8);
                acc[0][rbk] = __builtin_amdgcn_mfma_f32_16x16x32_f16(w2f[0][t], bfr, acc[0][rbk], 0, 0, 0);
                acc[1][rbk] = __builtin_amdgcn_mfma_f32_16x16x32_f16(w2f[1][t], bfr, acc[1][rbk], 0, 0, 0);
            }
        // stats2
#pragma unroll
        for (int ob = 0; ob < 2; ++ob)
#pragma unroll
            for (int rbk = 0; rbk < 4; ++rbk) {
                ssum[ob] += acc[ob][rbk];
                ssq[ob]  += acc[ob][rbk]*acc[ob][rbk];
            }
        // per-pair max/min via shuffle reduce over m (lanes xor 1,2,4,8)
#pragma unroll
        for (int ob = 0; ob < 2; ++ob)
#pragma unroll
            for (int pr = 0; pr < 2; ++pr) {
                f32x4 a0 = acc[ob][pr*2], a1 = acc[ob][pr*2 + 1];
                f32x4 vmx, vmn;
#pragma unroll
                for (int c = 0; c < 4; ++c) {
                    vmx[c] = fmaxf(a0[c], a1[c]);
                    vmn[c] = fminf(a0[c], a1[c]);
                }
#pragma unroll
                for (int off = 1; off < 16; off <<= 1)
#pragma unroll
                    for (int c = 0; c < 4; ++c) {
                        vmx[c] = fmaxf(vmx[c], __shfl_xor(vmx[c], off));
                        vmn[c] = fminf(vmn[c], __shfl_xor(vmn[c], off));
                    }
                if (m == 0) {
                    int p = tile*2 + pr;
                    int o0 = wid*32 + ob*16 + q*4;
                    *(f32x4*)(wsmax + (size_t)p*CC + o0) = vmx;
                    *(f32x4*)(wsmin + (size_t)p*CC + o0) = vmn;
                }
            }
    }
#pragma unroll
    for (int ob = 0; ob < 2; ++ob)
#pragma unroll
        for (int c = 0; c < 4; ++c) {
            float v = ssum[ob][c], v2 = ssq[ob][c];
#pragma unroll
            for (int off = 1; off < 16; off <<= 1) {
                v  += __shfl_xor(v,  off);
                v2 += __shfl_xor(v2, off);
            }
            if (m == 0) {
                int o = wid*32 + ob*16 + q*4 + c;
                atomicAdd(&gsum2[o], v);
                atomicAdd(&gsumsq2[o], v2);
            }
        }
}

// ---------------- epilogue: bn2+relu on max/min, transpose to (B,C,N) ----------------
__global__ void __launch_bounds__(256) k_epilogue(const float* __restrict__ wsmax,
                                                  const float* __restrict__ wsmin,
                                                  const float* __restrict__ ab2,
                                                  float* __restrict__ out) {
    __shared__ float t[128*65];
    int b = blockIdx.y;
    int n0 = blockIdx.x * 64;
    int tid = threadIdx.x;
#pragma unroll
    for (int i = 0; i < 32; ++i) {
        int idx = i*256 + tid;
        int nl = idx >> 7, o = idx & 127;
        int n = n0 + nl;
        float v = 0.f;
        if (n < NN) {
            float a = ab2[o], cc = ab2[CC + o];
            size_t p = (size_t)b*NN + n;
            float z = (a >= 0.f) ? wsmax[p*CC + o] : wsmin[p*CC + o];
            v = fmaf(a, z, cc);
            v = v > 0.f ? v : 0.f;
        }
        t[o*65 + nl] = v;
    }
    __syncthreads();
#pragma unroll
    for (int i = 0; i < 32; ++i) {
        int idx = i*256 + tid;
        int o = idx >> 6, nl = idx & 63;
        int n = n0 + nl;
        if (n < NN) out[((size_t)b*CC + o)*NN + n] = t[o*65 + nl];
    }
}

extern "C" void kernel_launch(void* const* d_in, const int* in_sizes, int n_in,
                              void* d_out, int out_size, void* d_ws, size_t ws_size,
                              hipStream_t stream) {
    const float* x      = (const float*)d_in[0];
    const float* coords = (const float*)d_in[1];
    const float* w1     = (const float*)d_in[2];
    const float* g1     = (const float*)d_in[3];
    const float* b1     = (const float*)d_in[4];
    const float* w2     = (const float*)d_in[5];
    const float* g2     = (const float*)d_in[6];
    const float* b2     = (const float*)d_in[7];
    float* out = (float*)d_out;

    char* ws = (char*)d_ws;
    size_t off = 0;
    int* knn_idx = (int*)(ws + off);   off += (size_t)ROWS * sizeof(int);        // 3.32 MB
    float* stats = (float*)(ws + off); off += 1024 * sizeof(float);
    float* gsum1 = stats,       *gsq1 = stats + 128;
    float* gsum2 = stats + 256, *gsq2 = stats + 384;
    float* ab1   = stats + 512;
    float* ab2   = stats + 768;
    __half* feats = (__half*)(ws + off); off += (size_t)BB*NN*DD * sizeof(__half); // 3.32 MB
    __half* w1h   = (__half*)(ws + off); off += CC*CC * sizeof(__half);
    __half* w2h   = (__half*)(ws + off); off += CC*CC * sizeof(__half);
    float* wsmax = (float*)(ws + off);  off += (size_t)PAIRS*CC * sizeof(float);  // 13.3 MB
    float* wsmin = (float*)(ws + off);  off += (size_t)PAIRS*CC * sizeof(float);  // 13.3 MB
    (void)ws_size; (void)in_sizes; (void)n_in; (void)out_size;

    hipMemsetAsync(stats, 0, 512 * sizeof(float), stream);

    dim3 gT((NN + 63)/64, BB);
    k_prep_feats<<<gT, 256, 0, stream>>>(x, feats);
    k_convert_w<<<64, 256, 0, stream>>>(w1, w2, w1h, w2h);
    k_knn<<<PAIRS, 64, 0, stream>>>(coords, knn_idx);
    k_mm1_mfma<<<GRID_MM, 256, 0, stream>>>(feats, knn_idx, w1h, gsum1, gsq1);
    k_finalize<<<1, CC, 0, stream>>>(gsum1, gsq1, g1, b1, ab1);
    k_fused_mfma<<<GRID_MM, 256, 0, stream>>>(feats, knn_idx, w1h, w2h, ab1,
                                              gsum2, gsq2, wsmax, wsmin);
    k_finalize<<<1, CC, 0, stream>>>(gsum2, gsq2, g2, b2, ab2);
    dim3 gE((NN + 63)/64, BB);
    k_epilogue<<<gE, 256, 0, stream>>>(wsmax, wsmin, ab2, out);
}

// Round 5
// 594.001 us; speedup vs baseline: 1.1190x; 1.1190x over previous
//
#include <hip/hip_runtime.h>
#include <hip/hip_fp16.h>
#include <stdint.h>

#define BB 16
#define NN 1620
#define DD 64
#define CC 128
#define KK 32
#define EPSV 1e-5f
#define PAIRS (BB*NN)            // 25920
#define ROWS  (PAIRS*KK)         // 829440
#define TILES (PAIRS/2)          // 12960 tiles of 64 rows
#define TPB_TILES 8
#define GRID_MM (TILES/TPB_TILES) // 1620
#define NCHUNK 26                // ceil(1620/64)

typedef _Float16 half8 __attribute__((ext_vector_type(8)));
typedef float f32x4 __attribute__((ext_vector_type(4)));

__device__ __forceinline__ float relu_(float v){ return v > 0.f ? v : 0.f; }

union H2U { __half2 h; unsigned u; };

// ---------------- x (B,D,N) fp32 -> feats (B,N,D) fp16 ----------------
__global__ void __launch_bounds__(256) k_prep_feats(const float* __restrict__ x,
                                                    __half* __restrict__ feats) {
    __shared__ float t[64*65];
    int b = blockIdx.y;
    int n0 = blockIdx.x * 64;
    int tid = threadIdx.x;
#pragma unroll
    for (int i = 0; i < 16; ++i) {
        int idx = i*256 + tid;
        int d = idx >> 6, nl = idx & 63;
        int n = n0 + nl;
        float v = 0.f;
        if (n < NN) v = x[((size_t)b*DD + d)*NN + n];
        t[d*65 + nl] = v;
    }
    __syncthreads();
#pragma unroll
    for (int i = 0; i < 8; ++i) {
        int idx = i*256 + tid;            // 64 nl x 32 d-pairs
        int nl = idx >> 5, dp = idx & 31;
        int n = n0 + nl;
        if (n < NN) {
            __half2 h = __floats2half2_rn(t[(dp*2)*65 + nl], t[(dp*2+1)*65 + nl]);
            *(__half2*)(feats + ((size_t)b*NN + n)*DD + dp*2) = h;
        }
    }
}

// ---------------- w fp32 -> fp16 (same [o][c] layout) ----------------
__global__ void k_convert_w(const float* __restrict__ w1, const float* __restrict__ w2,
                            __half* __restrict__ w1h, __half* __restrict__ w2h) {
    int i = blockIdx.x*256 + threadIdx.x;   // 64 blocks * 256 = 16384
    w1h[i] = __float2half(w1[i]);
    w2h[i] = __float2half(w2[i]);
}

// ---------------- KNN: one wave per query, radix-histogram rank selection ----------------
__global__ void __launch_bounds__(64) k_knn(const float* __restrict__ coords,
                                            int* __restrict__ idx_out) {
#pragma clang fp contract(off)
    __shared__ int hist[256];
    __shared__ unsigned bcast[2];   // [0]=bucket, [1]=count below bucket
    int p = blockIdx.x;
    int b = p / NN, n = p - b*NN;
    int lane = threadIdx.x;
    const float* cb = coords + (size_t)b*NN*3;
    float qx = cb[n*3+0], qy = cb[n*3+1], qz = cb[n*3+2];
    float sqn = (qx*qx + qy*qy) + qz*qz;

    unsigned key[NCHUNK];
#pragma unroll
    for (int i = 0; i < NCHUNK; ++i) {
        int m = lane + i*64;
        unsigned u = 0xFFFFFFFFu;
        if (m < NN) {
            float cx = cb[m*3+0], cy = cb[m*3+1], cz = cb[m*3+2];
            float sqm = (cx*cx + cy*cy) + cz*cz;
            float dot = (qx*cx + qy*cy) + qz*cz;
            float d = (sqn + sqm) - 2.0f*dot;
            unsigned t = __float_as_uint(d);
            u = (t & 0x80000000u) ? ~t : (t | 0x80000000u);
        }
        key[i] = u;
    }

    // ---- pass A: histogram on key[31:24] ----
#pragma unroll
    for (int i = 0; i < 4; ++i) hist[lane + i*64] = 0;
    __syncthreads();
#pragma unroll
    for (int i = 0; i < NCHUNK; ++i) {
        int m = lane + i*64;
        if (m < NN) atomicAdd(&hist[key[i] >> 24], 1);
    }
    __syncthreads();
    {
        int v0 = hist[lane*4+0], v1 = hist[lane*4+1], v2 = hist[lane*4+2], v3 = hist[lane*4+3];
        int c1 = v0+v1, c2 = c1+v2, c3 = c2+v3;
        int inc = c3;
#pragma unroll
        for (int off = 1; off < 64; off <<= 1) {
            int t = __shfl_up(inc, off);
            if (lane >= off) inc += t;
        }
        int base = inc - c3;
        if (base < KK) {
            int u0 = base+v0, u1 = base+c1, u2 = base+c2, u3 = base+c3;
            if      (u0 >= KK) { bcast[0] = lane*4+0; bcast[1] = base; }
            else if (u1 >= KK) { bcast[0] = lane*4+1; bcast[1] = u0; }
            else if (u2 >= KK) { bcast[0] = lane*4+2; bcast[1] = u1; }
            else if (u3 >= KK) { bcast[0] = lane*4+3; bcast[1] = u2; }
        }
    }
    __syncthreads();
    unsigned BA = bcast[0];
    int rA = KK - (int)bcast[1];
    __syncthreads();

    // ---- pass B: histogram on key[23:16] within bucket BA ----
#pragma unroll
    for (int i = 0; i < 4; ++i) hist[lane + i*64] = 0;
    __syncthreads();
#pragma unroll
    for (int i = 0; i < NCHUNK; ++i) {
        int m = lane + i*64;
        if (m < NN && (key[i] >> 24) == BA) atomicAdd(&hist[(key[i] >> 16) & 255], 1);
    }
    __syncthreads();
    {
        int v0 = hist[lane*4+0], v1 = hist[lane*4+1], v2 = hist[lane*4+2], v3 = hist[lane*4+3];
        int c1 = v0+v1, c2 = c1+v2, c3 = c2+v3;
        int inc = c3;
#pragma unroll
        for (int off = 1; off < 64; off <<= 1) {
            int t = __shfl_up(inc, off);
            if (lane >= off) inc += t;
        }
        int base = inc - c3;
        if (base < rA) {
            int u0 = base+v0, u1 = base+c1, u2 = base+c2, u3 = base+c3;
            if      (u0 >= rA) { bcast[0] = lane*4+0; bcast[1] = base; }
            else if (u1 >= rA) { bcast[0] = lane*4+1; bcast[1] = u0; }
            else if (u2 >= rA) { bcast[0] = lane*4+2; bcast[1] = u1; }
            else if (u3 >= rA) { bcast[0] = lane*4+3; bcast[1] = u2; }
        }
    }
    __syncthreads();
    unsigned prefix16 = (BA << 8) | bcast[0];
    int r = rA - (int)bcast[1];

    // ---- extract exact 32nd (key, m) pair ----
    unsigned long long fl = 0;
    for (int round = 0; round < r; ++round) {
        unsigned long long best = ~0ull;
#pragma unroll
        for (int i = 0; i < NCHUNK; ++i) {
            if ((key[i] >> 16) == prefix16) {
                unsigned long long v = ((unsigned long long)key[i] << 32) | (unsigned)(lane + i*64);
                if (v > fl && v < best) best = v;
            }
        }
#pragma unroll
        for (int off = 32; off; off >>= 1) {
            unsigned long long o = __shfl_xor(best, off, 64);
            if (o < best) best = o;
        }
        fl = best;
    }
    unsigned kstar = (unsigned)(fl >> 32);
    unsigned mstar = (unsigned)fl;

    int cnt = 0;
    unsigned long long mylow = (1ull << lane) - 1ull;
#pragma unroll
    for (int i = 0; i < NCHUNK; ++i) {
        unsigned m = lane + i*64;
        bool sel = (key[i] < kstar) || (key[i] == kstar && m <= mstar);
        unsigned long long bal = __ballot(sel);
        if (sel) {
            int pos = cnt + __popcll(bal & mylow);
            idx_out[p*KK + pos] = (int)m;
        }
        cnt += __popcll(bal);
    }
}

// ============ staging helpers: coalesced gather + XOR-swizzled LDS ============
// nf LDS layout: chunk (rbk, kc, m) -> slot rbk*256 + kc*16 + (m ^ kc), 16B each.
// Chunk holds nf[row = rbk*16 + m][k = kc*8 .. kc*8+7].
__device__ __forceinline__ void fill_bases(const int* __restrict__ knn_idx,
                                           int blk, int tid, int* rowb, int* ctrb) {
#pragma unroll
    for (int e = tid; e < TPB_TILES*64; e += 256) {
        int tile = blk*TPB_TILES + (e >> 6);
        int rr = e & 63;
        int p = tile*2 + (rr >> 5);
        int nb = knn_idx[p*KK + (rr & 31)];
        int b = p / NN;
        rowb[e] = (b*NN + nb)*DD;
        ctrb[e] = p*DD;
    }
}

// Thread handles fixed kc = tid&15, rows it*16 + (tid>>4).
// kc<8: neighbor chunk (8 consecutive lanes read one 128B row). kc>=8: center chunk.
__device__ __forceinline__ void stage_load(const __half* __restrict__ feats,
                                           const int* rowb, const int* ctrb,
                                           int tloc, int tid, uint4* A) {
    int kc = tid & 15;
#pragma unroll
    for (int it = 0; it < 4; ++it) {
        int row = it*16 + (tid >> 4);
        int e = tloc*64 + row;
        int ra = (kc < 8) ? (rowb[e] + kc*8) : (ctrb[e] + (kc-8)*8);
        A[it] = *(const uint4*)(feats + ra);
    }
}

__device__ __forceinline__ void stage_write(const __half* __restrict__ feats,
                                            const int* ctrb, int tloc, int tid,
                                            const uint4* A, __half* nf) {
    int kc = tid & 15;
#pragma unroll
    for (int it = 0; it < 4; ++it) {
        int row = it*16 + (tid >> 4);
        int e = tloc*64 + row;
        union { uint4 u; __half2 h[4]; } a, b, rr;
        a.u = A[it];
        if (kc < 8) {
            b.u = *(const uint4*)(feats + ctrb[e] + kc*8);
#pragma unroll
            for (int j = 0; j < 4; ++j) rr.h[j] = __hsub2(a.h[j], b.h[j]);
        } else {
            rr.u = a.u;
        }
        int C = (row >> 4)*256 + kc*16 + ((row & 15) ^ kc);   // XOR swizzle
        *(uint4*)(nf + C*8) = rr.u;
    }
}

// ---------------- pass 1: mm1 (MFMA) + stats1 ----------------
__global__ void __launch_bounds__(256, 4) k_mm1_mfma(const __half* __restrict__ feats,
                                                     const int* __restrict__ knn_idx,
                                                     const __half* __restrict__ w1h,
                                                     float* __restrict__ gsum,
                                                     float* __restrict__ gsumsq) {
    __shared__ __align__(16) __half nf[8192];          // 16 KB
    __shared__ int rowb[TPB_TILES*64];
    __shared__ int ctrb[TPB_TILES*64];
    int tid = threadIdx.x;
    int lane = tid & 63, wid = tid >> 6;
    int m = lane & 15, q = lane >> 4;

    fill_bases(knn_idx, blockIdx.x, tid, rowb, ctrb);

    half8 w1f[2][4];
#pragma unroll
    for (int ob = 0; ob < 2; ++ob)
#pragma unroll
        for (int t = 0; t < 4; ++t)
            w1f[ob][t] = *(const half8*)(w1h + (wid*32 + ob*16 + m)*CC + t*32 + q*8);

    f32x4 zero4 = {0.f, 0.f, 0.f, 0.f};
    f32x4 ssum[2] = {zero4, zero4}, ssq[2] = {zero4, zero4};

    __syncthreads();
    uint4 pf[4];
    stage_load(feats, rowb, ctrb, 0, tid, pf);

    for (int it = 0; it < TPB_TILES; ++it) {
        stage_write(feats, ctrb, it, tid, pf, nf);
        __syncthreads();
        if (it + 1 < TPB_TILES) stage_load(feats, rowb, ctrb, it + 1, tid, pf);

        f32x4 acc[2][4];
#pragma unroll
        for (int ob = 0; ob < 2; ++ob)
#pragma unroll
            for (int rbk = 0; rbk < 4; ++rbk) acc[ob][rbk] = zero4;

#pragma unroll
        for (int t = 0; t < 4; ++t) {
            int kct = t*4 + q;
            int sw = m ^ kct;
#pragma unroll
            for (int rbk = 0; rbk < 4; ++rbk) {
                half8 bfr = *(const half8*)(nf + (rbk*256 + kct*16 + sw)*8);
                acc[0][rbk] = __builtin_amdgcn_mfma_f32_16x16x32_f16(w1f[0][t], bfr, acc[0][rbk], 0, 0, 0);
                acc[1][rbk] = __builtin_amdgcn_mfma_f32_16x16x32_f16(w1f[1][t], bfr, acc[1][rbk], 0, 0, 0);
            }
        }
#pragma unroll
        for (int ob = 0; ob < 2; ++ob)
#pragma unroll
            for (int rbk = 0; rbk < 4; ++rbk) {
                ssum[ob] += acc[ob][rbk];
                ssq[ob]  += acc[ob][rbk]*acc[ob][rbk];
            }
        __syncthreads();
    }
#pragma unroll
    for (int ob = 0; ob < 2; ++ob)
#pragma unroll
        for (int c = 0; c < 4; ++c) {
            float v = ssum[ob][c], v2 = ssq[ob][c];
#pragma unroll
            for (int off = 1; off < 16; off <<= 1) {
                v  += __shfl_xor(v,  off);
                v2 += __shfl_xor(v2, off);
            }
            if (m == 0) {
                int o = wid*32 + ob*16 + q*4 + c;
                atomicAdd(&gsum[o], v);
                atomicAdd(&gsumsq[o], v2);
            }
        }
}

// ---------------- finalize bn params ----------------
__global__ void k_finalize(const float* __restrict__ gsum, const float* __restrict__ gsumsq,
                           const float* __restrict__ g, const float* __restrict__ bb,
                           float* __restrict__ ab) {
    int o = threadIdx.x;
    float cnt = (float)ROWS;
    float mean = gsum[o] / cnt;
    float var = gsumsq[o] / cnt - mean*mean;
    float a = g[o] * rsqrtf(var + EPSV);
    ab[o] = a;
    ab[CC + o] = bb[o] - mean*a;
}

// ---------------- pass 2: mm1 + bn1relu + mm2 + stats2 + per-pair max/min ----------------
__global__ void __launch_bounds__(256, 4) k_fused_mfma(const __half* __restrict__ feats,
                                                       const int* __restrict__ knn_idx,
                                                       const __half* __restrict__ w1h,
                                                       const __half* __restrict__ w2h,
                                                       const float* __restrict__ ab1,
                                                       float* __restrict__ gsum2,
                                                       float* __restrict__ gsumsq2,
                                                       float* __restrict__ wsmax,
                                                       float* __restrict__ wsmin) {
    __shared__ __align__(16) __half nf[8192];     // 16 KB, swizzled chunks
    __shared__ __align__(16) __half y1s[8192];    // 16 KB, same swizzled layout
    __shared__ __align__(16) float redmx[8*132];  // [pr*4+mgrp][132]
    __shared__ __align__(16) float redmn[8*132];
    __shared__ int rowb[TPB_TILES*64];
    __shared__ int ctrb[TPB_TILES*64];
    int tid = threadIdx.x;
    int lane = tid & 63, wid = tid >> 6;
    int m = lane & 15, q = lane >> 4;

    fill_bases(knn_idx, blockIdx.x, tid, rowb, ctrb);

    half8 w1f[2][4], w2f[2][4];
#pragma unroll
    for (int ob = 0; ob < 2; ++ob)
#pragma unroll
        for (int t = 0; t < 4; ++t) {
            int o = wid*32 + ob*16 + m;
            w1f[ob][t] = *(const half8*)(w1h + o*CC + t*32 + q*8);
            w2f[ob][t] = *(const half8*)(w2h + o*CC + t*32 + q*8);
        }
    f32x4 a1v[2], c1v[2];
#pragma unroll
    for (int ob = 0; ob < 2; ++ob) {
        a1v[ob] = *(const f32x4*)(ab1 + wid*32 + ob*16 + q*4);
        c1v[ob] = *(const f32x4*)(ab1 + CC + wid*32 + ob*16 + q*4);
    }
    f32x4 zero4 = {0.f, 0.f, 0.f, 0.f};
    f32x4 ssum[2] = {zero4, zero4}, ssq[2] = {zero4, zero4};

    __syncthreads();
    uint4 pf[4];
    stage_load(feats, rowb, ctrb, 0, tid, pf);

    for (int it = 0; it < TPB_TILES; ++it) {
        int tile = blockIdx.x * TPB_TILES + it;
        stage_write(feats, ctrb, it, tid, pf, nf);
        __syncthreads();                               // B1
        if (it + 1 < TPB_TILES) stage_load(feats, rowb, ctrb, it + 1, tid, pf);

        f32x4 acc[2][4];
#pragma unroll
        for (int ob = 0; ob < 2; ++ob)
#pragma unroll
            for (int rbk = 0; rbk < 4; ++rbk) acc[ob][rbk] = zero4;

        // mm1: z1^T = w1 . nf^T
#pragma unroll
        for (int t = 0; t < 4; ++t) {
            int kct = t*4 + q;
            int sw = m ^ kct;
#pragma unroll
            for (int rbk = 0; rbk < 4; ++rbk) {
                half8 bfr = *(const half8*)(nf + (rbk*256 + kct*16 + sw)*8);
                acc[0][rbk] = __builtin_amdgcn_mfma_f32_16x16x32_f16(w1f[0][t], bfr, acc[0][rbk], 0, 0, 0);
                acc[1][rbk] = __builtin_amdgcn_mfma_f32_16x16x32_f16(w1f[1][t], bfr, acc[1][rbk], 0, 0, 0);
            }
        }
        // bn1 + relu, write y1 in swizzled chunk layout
#pragma unroll
        for (int ob = 0; ob < 2; ++ob)
#pragma unroll
            for (int rbk = 0; rbk < 4; ++rbk) {
                f32x4 z = acc[ob][rbk];
                float y0 = relu_(fmaf(a1v[ob][0], z[0], c1v[ob][0]));
                float y1 = relu_(fmaf(a1v[ob][1], z[1], c1v[ob][1]));
                float y2 = relu_(fmaf(a1v[ob][2], z[2], c1v[ob][2]));
                float y3 = relu_(fmaf(a1v[ob][3], z[3], c1v[ob][3]));
                H2U p0, p1;
                p0.h = __floats2half2_rn(y0, y1);
                p1.h = __floats2half2_rn(y2, y3);
                int kcy = wid*4 + ob*2 + (q >> 1);       // channel-chunk index
                int C = rbk*256 + kcy*16 + (m ^ kcy);    // swizzled slot
                uint2 v; v.x = p0.u; v.y = p1.u;
                *(uint2*)(y1s + C*8 + (q & 1)*4) = v;
            }
        __syncthreads();                               // B2

        // mm2: z2^T = w2 . y1^T
#pragma unroll
        for (int ob = 0; ob < 2; ++ob)
#pragma unroll
            for (int rbk = 0; rbk < 4; ++rbk) acc[ob][rbk] = zero4;
#pragma unroll
        for (int t = 0; t < 4; ++t) {
            int kct = t*4 + q;
            int sw = m ^ kct;
#pragma unroll
            for (int rbk = 0; rbk < 4; ++rbk) {
                half8 bfr = *(const half8*)(y1s + (rbk*256 + kct*16 + sw)*8);
                acc[0][rbk] = __builtin_amdgcn_mfma_f32_16x16x32_f16(w2f[0][t], bfr, acc[0][rbk], 0, 0, 0);
                acc[1][rbk] = __builtin_amdgcn_mfma_f32_16x16x32_f16(w2f[1][t], bfr, acc[1][rbk], 0, 0, 0);
            }
        }
        // stats2
#pragma unroll
        for (int ob = 0; ob < 2; ++ob)
#pragma unroll
            for (int rbk = 0; rbk < 4; ++rbk) {
                ssum[ob] += acc[ob][rbk];
                ssq[ob]  += acc[ob][rbk]*acc[ob][rbk];
            }
        // per-pair max/min: rbk-pair reduce in regs, 2 quad-perm DPP steps (xor 1,2),
        // then lanes m%4==0 stage to LDS; coalesced global write after barrier.
#pragma unroll
        for (int ob = 0; ob < 2; ++ob)
#pragma unroll
            for (int pr = 0; pr < 2; ++pr) {
                f32x4 a0 = acc[ob][pr*2], a1 = acc[ob][pr*2 + 1];
                f32x4 vmx, vmn;
#pragma unroll
                for (int c = 0; c < 4; ++c) {
                    vmx[c] = fmaxf(a0[c], a1[c]);
                    vmn[c] = fminf(a0[c], a1[c]);
                }
#pragma unroll
                for (int off = 1; off < 4; off <<= 1)
#pragma unroll
                    for (int c = 0; c < 4; ++c) {
                        vmx[c] = fmaxf(vmx[c], __shfl_xor(vmx[c], off));
                        vmn[c] = fminf(vmn[c], __shfl_xor(vmn[c], off));
                    }
                if ((m & 3) == 0) {
                    int mg = m >> 2;
                    int o0 = wid*32 + ob*16 + q*4;
                    *(f32x4*)(redmx + (pr*4 + mg)*132 + o0) = vmx;
                    *(f32x4*)(redmn + (pr*4 + mg)*132 + o0) = vmn;
                }
            }
        __syncthreads();                               // B3
        {
            int pr = tid >> 7, o = tid & 127;
            float M  = redmx[(pr*4+0)*132 + o];
            float Mn = redmn[(pr*4+0)*132 + o];
#pragma unroll
            for (int mg = 1; mg < 4; ++mg) {
                M  = fmaxf(M,  redmx[(pr*4+mg)*132 + o]);
                Mn = fminf(Mn, redmn[(pr*4+mg)*132 + o]);
            }
            int p = tile*2 + pr;
            wsmax[(size_t)p*CC + o] = M;
            wsmin[(size_t)p*CC + o] = Mn;
        }
    }
#pragma unroll
    for (int ob = 0; ob < 2; ++ob)
#pragma unroll
        for (int c = 0; c < 4; ++c) {
            float v = ssum[ob][c], v2 = ssq[ob][c];
#pragma unroll
            for (int off = 1; off < 16; off <<= 1) {
                v  += __shfl_xor(v,  off);
                v2 += __shfl_xor(v2, off);
            }
            if (m == 0) {
                int o = wid*32 + ob*16 + q*4 + c;
                atomicAdd(&gsum2[o], v);
                atomicAdd(&gsumsq2[o], v2);
            }
        }
}

// ---------------- epilogue: bn2+relu on max/min, transpose to (B,C,N) ----------------
__global__ void __launch_bounds__(256) k_epilogue(const float* __restrict__ wsmax,
                                                  const float* __restrict__ wsmin,
                                                  const float* __restrict__ ab2,
                                                  float* __restrict__ out) {
    __shared__ float t[128*65];
    int b = blockIdx.y;
    int n0 = blockIdx.x * 64;
    int tid = threadIdx.x;
#pragma unroll
    for (int i = 0; i < 32; ++i) {
        int idx = i*256 + tid;
        int nl = idx >> 7, o = idx & 127;
        int n = n0 + nl;
        float v = 0.f;
        if (n < NN) {
            float a = ab2[o], cc = ab2[CC + o];
            size_t p = (size_t)b*NN + n;
            float z = (a >= 0.f) ? wsmax[p*CC + o] : wsmin[p*CC + o];
            v = fmaf(a, z, cc);
            v = v > 0.f ? v : 0.f;
        }
        t[o*65 + nl] = v;
    }
    __syncthreads();
#pragma unroll
    for (int i = 0; i < 32; ++i) {
        int idx = i*256 + tid;
        int o = idx >> 6, nl = idx & 63;
        int n = n0 + nl;
        if (n < NN) out[((size_t)b*CC + o)*NN + n] = t[o*65 + nl];
    }
}

extern "C" void kernel_launch(void* const* d_in, const int* in_sizes, int n_in,
                              void* d_out, int out_size, void* d_ws, size_t ws_size,
                              hipStream_t stream) {
    const float* x      = (const float*)d_in[0];
    const float* coords = (const float*)d_in[1];
    const float* w1     = (const float*)d_in[2];
    const float* g1     = (const float*)d_in[3];
    const float* b1     = (const float*)d_in[4];
    const float* w2     = (const float*)d_in[5];
    const float* g2     = (const float*)d_in[6];
    const float* b2     = (const float*)d_in[7];
    float* out = (float*)d_out;

    char* ws = (char*)d_ws;
    size_t off = 0;
    int* knn_idx = (int*)(ws + off);   off += (size_t)ROWS * sizeof(int);        // 3.32 MB
    float* stats = (float*)(ws + off); off += 1024 * sizeof(float);
    float* gsum1 = stats,       *gsq1 = stats + 128;
    float* gsum2 = stats + 256, *gsq2 = stats + 384;
    float* ab1   = stats + 512;
    float* ab2   = stats + 768;
    __half* feats = (__half*)(ws + off); off += (size_t)BB*NN*DD * sizeof(__half); // 3.32 MB
    __half* w1h   = (__half*)(ws + off); off += CC*CC * sizeof(__half);
    __half* w2h   = (__half*)(ws + off); off += CC*CC * sizeof(__half);
    float* wsmax = (float*)(ws + off);  off += (size_t)PAIRS*CC * sizeof(float);  // 13.3 MB
    float* wsmin = (float*)(ws + off);  off += (size_t)PAIRS*CC * sizeof(float);  // 13.3 MB
    (void)ws_size; (void)in_sizes; (void)n_in; (void)out_size;

    hipMemsetAsync(stats, 0, 512 * sizeof(float), stream);

    dim3 gT((NN + 63)/64, BB);
    k_prep_feats<<<gT, 256, 0, stream>>>(x, feats);
    k_convert_w<<<64, 256, 0, stream>>>(w1, w2, w1h, w2h);
    k_knn<<<PAIRS, 64, 0, stream>>>(coords, knn_idx);
    k_mm1_mfma<<<GRID_MM, 256, 0, stream>>>(feats, knn_idx, w1h, gsum1, gsq1);
    k_finalize<<<1, CC, 0, stream>>>(gsum1, gsq1, g1, b1, ab1);
    k_fused_mfma<<<GRID_MM, 256, 0, stream>>>(feats, knn_idx, w1h, w2h, ab1,
                                              gsum2, gsq2, wsmax, wsmin);
    k_finalize<<<1, CC, 0, stream>>>(gsum2, gsq2, g2, b2, ab2);
    dim3 gE((NN + 63)/64, BB);
    k_epilogue<<<gE, 256, 0, stream>>>(wsmax, wsmin, ab2, out);
}

// Round 6
// 529.387 us; speedup vs baseline: 1.2556x; 1.1221x over previous
//
#include <hip/hip_runtime.h>
#include <hip/hip_fp16.h>
#include <stdint.h>

#define BB 16
#define NN 1620
#define DD 64
#define CC 128
#define KK 32
#define EPSV 1e-5f
#define PAIRS (BB*NN)            // 25920
#define ROWS  (PAIRS*KK)         // 829440
#define TILES (PAIRS/2)          // 12960 tiles of 64 rows
#define TPB_TILES 8
#define GRID_MM (TILES/TPB_TILES) // 1620
#define NCHUNK 26                // ceil(1620/64)
#define GRAM_BLOCKS 128
#define MSTRIDE 12416            // 3*4096 mats + 64 vcf + 64 vf

typedef _Float16 half8 __attribute__((ext_vector_type(8)));
typedef float f32x4 __attribute__((ext_vector_type(4)));

__device__ __forceinline__ float relu_(float v){ return v > 0.f ? v : 0.f; }

union H2U { __half2 h; unsigned u; };

// ---------------- x (B,D,N) fp32 -> feats (B,N,D) fp16 ----------------
__global__ void __launch_bounds__(256) k_prep_feats(const float* __restrict__ x,
                                                    __half* __restrict__ feats) {
    __shared__ float t[64*65];
    int b = blockIdx.y;
    int n0 = blockIdx.x * 64;
    int tid = threadIdx.x;
#pragma unroll
    for (int i = 0; i < 16; ++i) {
        int idx = i*256 + tid;
        int d = idx >> 6, nl = idx & 63;
        int n = n0 + nl;
        float v = 0.f;
        if (n < NN) v = x[((size_t)b*DD + d)*NN + n];
        t[d*65 + nl] = v;
    }
    __syncthreads();
#pragma unroll
    for (int i = 0; i < 8; ++i) {
        int idx = i*256 + tid;            // 64 nl x 32 d-pairs
        int nl = idx >> 5, dp = idx & 31;
        int n = n0 + nl;
        if (n < NN) {
            __half2 h = __floats2half2_rn(t[(dp*2)*65 + nl], t[(dp*2+1)*65 + nl]);
            *(__half2*)(feats + ((size_t)b*NN + n)*DD + dp*2) = h;
        }
    }
}

// ---------------- w fp32 -> fp16 (same [o][c] layout) ----------------
__global__ void k_convert_w(const float* __restrict__ w1, const float* __restrict__ w2,
                            __half* __restrict__ w1h, __half* __restrict__ w2h) {
    int i = blockIdx.x*256 + threadIdx.x;   // 64 blocks * 256 = 16384
    w1h[i] = __float2half(w1[i]);
    w2h[i] = __float2half(w2[i]);
}

// ---------------- KNN: radix-histogram rank selection + neighbor-count histogram ----------------
__global__ void __launch_bounds__(64) k_knn(const float* __restrict__ coords,
                                            int* __restrict__ idx_out,
                                            int* __restrict__ cnt) {
#pragma clang fp contract(off)
    __shared__ int hist[256];
    __shared__ unsigned bcast[2];   // [0]=bucket, [1]=count below bucket
    int p = blockIdx.x;
    int b = p / NN, n = p - b*NN;
    int lane = threadIdx.x;
    const float* cb = coords + (size_t)b*NN*3;
    float qx = cb[n*3+0], qy = cb[n*3+1], qz = cb[n*3+2];
    float sqn = (qx*qx + qy*qy) + qz*qz;

    unsigned key[NCHUNK];
#pragma unroll
    for (int i = 0; i < NCHUNK; ++i) {
        int m = lane + i*64;
        unsigned u = 0xFFFFFFFFu;
        if (m < NN) {
            float cx = cb[m*3+0], cy = cb[m*3+1], cz = cb[m*3+2];
            float sqm = (cx*cx + cy*cy) + cz*cz;
            float dot = (qx*cx + qy*cy) + qz*cz;
            float d = (sqn + sqm) - 2.0f*dot;
            unsigned t = __float_as_uint(d);
            u = (t & 0x80000000u) ? ~t : (t | 0x80000000u);
        }
        key[i] = u;
    }

    // ---- pass A: histogram on key[31:24] ----
#pragma unroll
    for (int i = 0; i < 4; ++i) hist[lane + i*64] = 0;
    __syncthreads();
#pragma unroll
    for (int i = 0; i < NCHUNK; ++i) {
        int m = lane + i*64;
        if (m < NN) atomicAdd(&hist[key[i] >> 24], 1);
    }
    __syncthreads();
    {
        int v0 = hist[lane*4+0], v1 = hist[lane*4+1], v2 = hist[lane*4+2], v3 = hist[lane*4+3];
        int c1 = v0+v1, c2 = c1+v2, c3 = c2+v3;
        int inc = c3;
#pragma unroll
        for (int off = 1; off < 64; off <<= 1) {
            int t = __shfl_up(inc, off);
            if (lane >= off) inc += t;
        }
        int base = inc - c3;
        if (base < KK) {
            int u0 = base+v0, u1 = base+c1, u2 = base+c2, u3 = base+c3;
            if      (u0 >= KK) { bcast[0] = lane*4+0; bcast[1] = base; }
            else if (u1 >= KK) { bcast[0] = lane*4+1; bcast[1] = u0; }
            else if (u2 >= KK) { bcast[0] = lane*4+2; bcast[1] = u1; }
            else if (u3 >= KK) { bcast[0] = lane*4+3; bcast[1] = u2; }
        }
    }
    __syncthreads();
    unsigned BA = bcast[0];
    int rA = KK - (int)bcast[1];
    __syncthreads();

    // ---- pass B: histogram on key[23:16] within bucket BA ----
#pragma unroll
    for (int i = 0; i < 4; ++i) hist[lane + i*64] = 0;
    __syncthreads();
#pragma unroll
    for (int i = 0; i < NCHUNK; ++i) {
        int m = lane + i*64;
        if (m < NN && (key[i] >> 24) == BA) atomicAdd(&hist[(key[i] >> 16) & 255], 1);
    }
    __syncthreads();
    {
        int v0 = hist[lane*4+0], v1 = hist[lane*4+1], v2 = hist[lane*4+2], v3 = hist[lane*4+3];
        int c1 = v0+v1, c2 = c1+v2, c3 = c2+v3;
        int inc = c3;
#pragma unroll
        for (int off = 1; off < 64; off <<= 1) {
            int t = __shfl_up(inc, off);
            if (lane >= off) inc += t;
        }
        int base = inc - c3;
        if (base < rA) {
            int u0 = base+v0, u1 = base+c1, u2 = base+c2, u3 = base+c3;
            if      (u0 >= rA) { bcast[0] = lane*4+0; bcast[1] = base; }
            else if (u1 >= rA) { bcast[0] = lane*4+1; bcast[1] = u0; }
            else if (u2 >= rA) { bcast[0] = lane*4+2; bcast[1] = u1; }
            else if (u3 >= rA) { bcast[0] = lane*4+3; bcast[1] = u2; }
        }
    }
    __syncthreads();
    unsigned prefix16 = (BA << 8) | bcast[0];
    int r = rA - (int)bcast[1];

    // ---- extract exact 32nd (key, m) pair ----
    unsigned long long fl = 0;
    for (int round = 0; round < r; ++round) {
        unsigned long long best = ~0ull;
#pragma unroll
        for (int i = 0; i < NCHUNK; ++i) {
            if ((key[i] >> 16) == prefix16) {
                unsigned long long v = ((unsigned long long)key[i] << 32) | (unsigned)(lane + i*64);
                if (v > fl && v < best) best = v;
            }
        }
#pragma unroll
        for (int off = 32; off; off >>= 1) {
            unsigned long long o = __shfl_xor(best, off, 64);
            if (o < best) best = o;
        }
        fl = best;
    }
    unsigned kstar = (unsigned)(fl >> 32);
    unsigned mstar = (unsigned)fl;

    int cnt_ = 0;
    unsigned long long mylow = (1ull << lane) - 1ull;
#pragma unroll
    for (int i = 0; i < NCHUNK; ++i) {
        unsigned m = lane + i*64;
        bool sel = (key[i] < kstar) || (key[i] == kstar && m <= mstar);
        unsigned long long bal = __ballot(sel);
        if (sel) {
            int pos = cnt_ + __popcll(bal & mylow);
            idx_out[p*KK + pos] = (int)m;
            atomicAdd(&cnt[b*NN + (int)m], 1);
        }
        cnt_ += __popcll(bal);
    }
}

// ---------------- gather-sum: s_p = sum_k f_nb(p,k), fp32 ----------------
__global__ void __launch_bounds__(256) k_gather_sum(const __half* __restrict__ feats,
                                                    const int* __restrict__ knn_idx,
                                                    float* __restrict__ s_arr) {
    int w = threadIdx.x >> 6, lane = threadIdx.x & 63;
    int p = blockIdx.x*4 + w;
    int b = p / NN;
    int bbase = b*NN;
    int idx = 0;
    if (lane < KK) idx = knn_idx[p*KK + lane];
    float s = 0.f;
#pragma unroll
    for (int k = 0; k < KK; ++k) {
        int nb = __shfl(idx, k);
        s += __half2float(feats[((size_t)(bbase + nb))*DD + lane]);
    }
    s_arr[(size_t)p*DD + lane] = s;
}

// ---------------- gram: per-block partial M1/M2/M3 + vectors ----------------
// M1 = sum cnt_m f f^T, M2 = sum s_p f_p^T, M3 = sum f f^T, vcf = sum cnt f, vf = sum f
__global__ void __launch_bounds__(256) k_gram(const __half* __restrict__ feats,
                                              const float* __restrict__ s_arr,
                                              const int* __restrict__ cnt,
                                              float* __restrict__ Mpart) {
    __shared__ float fs[4][64];
    __shared__ float ss[4][64];
    __shared__ float cs[4];
    int tid = threadIdx.x;
    int rt = tid >> 4, ct = tid & 15;
    int r0 = rt*4, c0 = ct*4;
    float m1a[4][4] = {{0}}, m2a[4][4] = {{0}}, m3a[4][4] = {{0}};
    float vcf4[4] = {0,0,0,0}, vf4[4] = {0,0,0,0};

    int per = (PAIRS + GRAM_BLOCKS - 1)/GRAM_BLOCKS;   // 203
    int p0 = blockIdx.x * per;
    int p1 = p0 + per; if (p1 > PAIRS) p1 = PAIRS;

    for (int pc = p0; pc < p1; pc += 4) {
        __syncthreads();
        int sub = tid >> 6, l = tid & 63;
        int pp = pc + sub;
        if (pp < p1) {
            fs[sub][l] = __half2float(feats[(size_t)pp*DD + l]);
            ss[sub][l] = s_arr[(size_t)pp*DD + l];
            if (l == 0) cs[sub] = (float)cnt[pp];
        }
        __syncthreads();
        int e = p1 - pc; if (e > 4) e = 4;
        for (int j = 0; j < e; ++j) {
            float cn = cs[j];
            float fr[4], sr[4], fc[4];
#pragma unroll
            for (int a = 0; a < 4; ++a) { fr[a] = fs[j][r0+a]; sr[a] = ss[j][r0+a]; fc[a] = fs[j][c0+a]; }
#pragma unroll
            for (int a = 0; a < 4; ++a) {
                float cfr = cn * fr[a];
#pragma unroll
                for (int bc = 0; bc < 4; ++bc) {
                    m1a[a][bc] = fmaf(cfr,   fc[bc], m1a[a][bc]);
                    m2a[a][bc] = fmaf(sr[a], fc[bc], m2a[a][bc]);
                    m3a[a][bc] = fmaf(fr[a], fc[bc], m3a[a][bc]);
                }
                if (ct == 0) { vcf4[a] += cfr; vf4[a] += fr[a]; }
            }
        }
    }
    float* out = Mpart + (size_t)blockIdx.x * MSTRIDE;
#pragma unroll
    for (int a = 0; a < 4; ++a)
#pragma unroll
        for (int bc = 0; bc < 4; ++bc) {
            int idx = (r0+a)*64 + c0+bc;
            out[idx]        = m1a[a][bc];
            out[4096 + idx] = m2a[a][bc];
            out[8192 + idx] = m3a[a][bc];
        }
    if (ct == 0)
#pragma unroll
        for (int a = 0; a < 4; ++a) {
            out[12288 + r0+a] = vcf4[a];
            out[12352 + r0+a] = vf4[a];
        }
}

__global__ void __launch_bounds__(256) k_gram_reduce(const float* __restrict__ Mpart,
                                                     float* __restrict__ Mfin) {
    int e = blockIdx.x*256 + threadIdx.x;
    if (e < MSTRIDE) {
        float s = 0.f;
        for (int p = 0; p < GRAM_BLOCKS; ++p) s += Mpart[(size_t)p*MSTRIDE + e];
        Mfin[e] = s;
    }
}

// ---------------- stats1 from Gram: one block per output channel o ----------------
__global__ void __launch_bounds__(256) k_stats1(const float* __restrict__ M,
                                                const __half* __restrict__ w1h,
                                                const float* __restrict__ g1,
                                                const float* __restrict__ b1,
                                                float* __restrict__ ab1) {
    __shared__ float wl[64], wr[64];
    __shared__ float redA[256], redB[256];
    int o = blockIdx.x, tid = threadIdx.x;
    if (tid < 64)       wl[tid]    = __half2float(w1h[o*CC + tid]);
    else if (tid < 128) wr[tid-64] = __half2float(w1h[o*CC + tid]);
    __syncthreads();
    const float* M1 = M;
    const float* M2 = M + 4096;
    const float* M3 = M + 8192;
    const float* vcf = M + 12288;
    const float* vf  = M + 12352;
    float part = 0.f;
    for (int e = tid; e < 4096; e += 256) {
        int i = e >> 6, j = e & 63;
        float m1 = M1[e], m2 = M2[e], m2t = M2[j*64 + i], m3 = M3[e];
        float A  = m1 - m2 - m2t + 32.f*m3;   // sum u u^T
        float Bc = m2 - 32.f*m3;              // sum u v^T
        part += wl[i]*(A*wl[j] + 2.f*Bc*wr[j]) + 32.f*wr[i]*m3*wr[j];
    }
    float psum = 0.f;
    if (tid < 64) psum = wl[tid]*(vcf[tid] - 32.f*vf[tid]) + 32.f*wr[tid]*vf[tid];
    redA[tid] = part; redB[tid] = psum;
    __syncthreads();
    for (int s = 128; s > 0; s >>= 1) {
        if (tid < s) { redA[tid] += redA[tid+s]; redB[tid] += redB[tid+s]; }
        __syncthreads();
    }
    if (tid == 0) {
        float sumsq = redA[0], sum = redB[0];
        float mean = sum / (float)ROWS;
        float var  = sumsq / (float)ROWS - mean*mean;
        float a = g1[o] * rsqrtf(var + EPSV);
        ab1[o] = a;
        ab1[CC + o] = b1[o] - mean*a;
    }
}

// ============ staging helpers: coalesced gather + XOR-swizzled LDS ============
__device__ __forceinline__ void fill_bases(const int* __restrict__ knn_idx,
                                           int blk, int tid, int* rowb, int* ctrb) {
#pragma unroll
    for (int e = tid; e < TPB_TILES*64; e += 256) {
        int tile = blk*TPB_TILES + (e >> 6);
        int rr = e & 63;
        int p = tile*2 + (rr >> 5);
        int nb = knn_idx[p*KK + (rr & 31)];
        int b = p / NN;
        rowb[e] = (b*NN + nb)*DD;
        ctrb[e] = p*DD;
    }
}

__device__ __forceinline__ void stage_load(const __half* __restrict__ feats,
                                           const int* rowb, const int* ctrb,
                                           int tloc, int tid, uint4* A) {
    int kc = tid & 15;
#pragma unroll
    for (int it = 0; it < 4; ++it) {
        int row = it*16 + (tid >> 4);
        int e = tloc*64 + row;
        int ra = (kc < 8) ? (rowb[e] + kc*8) : (ctrb[e] + (kc-8)*8);
        A[it] = *(const uint4*)(feats + ra);
    }
}

__device__ __forceinline__ void stage_write(const __half* __restrict__ feats,
                                            const int* ctrb, int tloc, int tid,
                                            const uint4* A, __half* nf) {
    int kc = tid & 15;
#pragma unroll
    for (int it = 0; it < 4; ++it) {
        int row = it*16 + (tid >> 4);
        int e = tloc*64 + row;
        union { uint4 u; __half2 h[4]; } a, b, rr;
        a.u = A[it];
        if (kc < 8) {
            b.u = *(const uint4*)(feats + ctrb[e] + kc*8);
#pragma unroll
            for (int j = 0; j < 4; ++j) rr.h[j] = __hsub2(a.h[j], b.h[j]);
        } else {
            rr.u = a.u;
        }
        int C = (row >> 4)*256 + kc*16 + ((row & 15) ^ kc);   // XOR swizzle
        *(uint4*)(nf + C*8) = rr.u;
    }
}

// ---------------- finalize bn params (layer 2) ----------------
__global__ void k_finalize(const float* __restrict__ gsum, const float* __restrict__ gsumsq,
                           const float* __restrict__ g, const float* __restrict__ bb,
                           float* __restrict__ ab) {
    int o = threadIdx.x;
    float cnt = (float)ROWS;
    float mean = gsum[o] / cnt;
    float var = gsumsq[o] / cnt - mean*mean;
    float a = g[o] * rsqrtf(var + EPSV);
    ab[o] = a;
    ab[CC + o] = bb[o] - mean*a;
}

// ---------------- fused: mm1 + bn1relu + mm2 + stats2 + per-pair max/min ----------------
__global__ void __launch_bounds__(256, 4) k_fused_mfma(const __half* __restrict__ feats,
                                                       const int* __restrict__ knn_idx,
                                                       const __half* __restrict__ w1h,
                                                       const __half* __restrict__ w2h,
                                                       const float* __restrict__ ab1,
                                                       float* __restrict__ gsum2,
                                                       float* __restrict__ gsumsq2,
                                                       float* __restrict__ wsmax,
                                                       float* __restrict__ wsmin) {
    __shared__ __align__(16) __half nf[8192];     // 16 KB, swizzled chunks
    __shared__ __align__(16) __half y1s[8192];    // 16 KB, same swizzled layout
    __shared__ __align__(16) float redmx[8*132];
    __shared__ __align__(16) float redmn[8*132];
    __shared__ int rowb[TPB_TILES*64];
    __shared__ int ctrb[TPB_TILES*64];
    int tid = threadIdx.x;
    int lane = tid & 63, wid = tid >> 6;
    int m = lane & 15, q = lane >> 4;

    fill_bases(knn_idx, blockIdx.x, tid, rowb, ctrb);

    half8 w1f[2][4], w2f[2][4];
#pragma unroll
    for (int ob = 0; ob < 2; ++ob)
#pragma unroll
        for (int t = 0; t < 4; ++t) {
            int o = wid*32 + ob*16 + m;
            w1f[ob][t] = *(const half8*)(w1h + o*CC + t*32 + q*8);
            w2f[ob][t] = *(const half8*)(w2h + o*CC + t*32 + q*8);
        }
    f32x4 a1v[2], c1v[2];
#pragma unroll
    for (int ob = 0; ob < 2; ++ob) {
        a1v[ob] = *(const f32x4*)(ab1 + wid*32 + ob*16 + q*4);
        c1v[ob] = *(const f32x4*)(ab1 + CC + wid*32 + ob*16 + q*4);
    }
    f32x4 zero4 = {0.f, 0.f, 0.f, 0.f};
    f32x4 ssum[2] = {zero4, zero4}, ssq[2] = {zero4, zero4};

    __syncthreads();
    uint4 pf[4];
    stage_load(feats, rowb, ctrb, 0, tid, pf);

    for (int it = 0; it < TPB_TILES; ++it) {
        int tile = blockIdx.x * TPB_TILES + it;
        stage_write(feats, ctrb, it, tid, pf, nf);
        __syncthreads();                               // B1
        if (it + 1 < TPB_TILES) stage_load(feats, rowb, ctrb, it + 1, tid, pf);

        f32x4 acc[2][4];
#pragma unroll
        for (int ob = 0; ob < 2; ++ob)
#pragma unroll
            for (int rbk = 0; rbk < 4; ++rbk) acc[ob][rbk] = zero4;

        // mm1: z1^T = w1 . nf^T
#pragma unroll
        for (int t = 0; t < 4; ++t) {
            int kct = t*4 + q;
            int sw = m ^ kct;
#pragma unroll
            for (int rbk = 0; rbk < 4; ++rbk) {
                half8 bfr = *(const half8*)(nf + (rbk*256 + kct*16 + sw)*8);
                acc[0][rbk] = __builtin_amdgcn_mfma_f32_16x16x32_f16(w1f[0][t], bfr, acc[0][rbk], 0, 0, 0);
                acc[1][rbk] = __builtin_amdgcn_mfma_f32_16x16x32_f16(w1f[1][t], bfr, acc[1][rbk], 0, 0, 0);
            }
        }
        // bn1 + relu, write y1 in swizzled chunk layout
#pragma unroll
        for (int ob = 0; ob < 2; ++ob)
#pragma unroll
            for (int rbk = 0; rbk < 4; ++rbk) {
                f32x4 z = acc[ob][rbk];
                float y0 = relu_(fmaf(a1v[ob][0], z[0], c1v[ob][0]));
                float y1 = relu_(fmaf(a1v[ob][1], z[1], c1v[ob][1]));
                float y2 = relu_(fmaf(a1v[ob][2], z[2], c1v[ob][2]));
                float y3 = relu_(fmaf(a1v[ob][3], z[3], c1v[ob][3]));
                H2U p0, p1;
                p0.h = __floats2half2_rn(y0, y1);
                p1.h = __floats2half2_rn(y2, y3);
                int kcy = wid*4 + ob*2 + (q >> 1);
                int C = rbk*256 + kcy*16 + (m ^ kcy);
                uint2 v; v.x = p0.u; v.y = p1.u;
                *(uint2*)(y1s + C*8 + (q & 1)*4) = v;
            }
        __syncthreads();                               // B2

        // mm2: z2^T = w2 . y1^T
#pragma unroll
        for (int ob = 0; ob < 2; ++ob)
#pragma unroll
            for (int rbk = 0; rbk < 4; ++rbk) acc[ob][rbk] = zero4;
#pragma unroll
        for (int t = 0; t < 4; ++t) {
            int kct = t*4 + q;
            int sw = m ^ kct;
#pragma unroll
            for (int rbk = 0; rbk < 4; ++rbk) {
                half8 bfr = *(const half8*)(y1s + (rbk*256 + kct*16 + sw)*8);
                acc[0][rbk] = __builtin_amdgcn_mfma_f32_16x16x32_f16(w2f[0][t], bfr, acc[0][rbk], 0, 0, 0);
                acc[1][rbk] = __builtin_amdgcn_mfma_f32_16x16x32_f16(w2f[1][t], bfr, acc[1][rbk], 0, 0, 0);
            }
        }
        // stats2
#pragma unroll
        for (int ob = 0; ob < 2; ++ob)
#pragma unroll
            for (int rbk = 0; rbk < 4; ++rbk) {
                ssum[ob] += acc[ob][rbk];
                ssq[ob]  += acc[ob][rbk]*acc[ob][rbk];
            }
        // per-pair max/min
#pragma unroll
        for (int ob = 0; ob < 2; ++ob)
#pragma unroll
            for (int pr = 0; pr < 2; ++pr) {
                f32x4 a0 = acc[ob][pr*2], a1 = acc[ob][pr*2 + 1];
                f32x4 vmx, vmn;
#pragma unroll
                for (int c = 0; c < 4; ++c) {
                    vmx[c] = fmaxf(a0[c], a1[c]);
                    vmn[c] = fminf(a0[c], a1[c]);
                }
#pragma unroll
                for (int off = 1; off < 4; off <<= 1)
#pragma unroll
                    for (int c = 0; c < 4; ++c) {
                        vmx[c] = fmaxf(vmx[c], __shfl_xor(vmx[c], off));
                        vmn[c] = fminf(vmn[c], __shfl_xor(vmn[c], off));
                    }
                if ((m & 3) == 0) {
                    int mg = m >> 2;
                    int o0 = wid*32 + ob*16 + q*4;
                    *(f32x4*)(redmx + (pr*4 + mg)*132 + o0) = vmx;
                    *(f32x4*)(redmn + (pr*4 + mg)*132 + o0) = vmn;
                }
            }
        __syncthreads();                               // B3
        {
            int pr = tid >> 7, o = tid & 127;
            float M  = redmx[(pr*4+0)*132 + o];
            float Mn = redmn[(pr*4+0)*132 + o];
#pragma unroll
            for (int mg = 1; mg < 4; ++mg) {
                M  = fmaxf(M,  redmx[(pr*4+mg)*132 + o]);
                Mn = fminf(Mn, redmn[(pr*4+mg)*132 + o]);
            }
            int p = tile*2 + pr;
            wsmax[(size_t)p*CC + o] = M;
            wsmin[(size_t)p*CC + o] = Mn;
        }
    }
#pragma unroll
    for (int ob = 0; ob < 2; ++ob)
#pragma unroll
        for (int c = 0; c < 4; ++c) {
            float v = ssum[ob][c], v2 = ssq[ob][c];
#pragma unroll
            for (int off = 1; off < 16; off <<= 1) {
                v  += __shfl_xor(v,  off);
                v2 += __shfl_xor(v2, off);
            }
            if (m == 0) {
                int o = wid*32 + ob*16 + q*4 + c;
                atomicAdd(&gsum2[o], v);
                atomicAdd(&gsumsq2[o], v2);
            }
        }
}

// ---------------- epilogue: bn2+relu on max/min, transpose to (B,C,N) ----------------
__global__ void __launch_bounds__(256) k_epilogue(const float* __restrict__ wsmax,
                                                  const float* __restrict__ wsmin,
                                                  const float* __restrict__ ab2,
                                                  float* __restrict__ out) {
    __shared__ float t[128*65];
    int b = blockIdx.y;
    int n0 = blockIdx.x * 64;
    int tid = threadIdx.x;
#pragma unroll
    for (int i = 0; i < 32; ++i) {
        int idx = i*256 + tid;
        int nl = idx >> 7, o = idx & 127;
        int n = n0 + nl;
        float v = 0.f;
        if (n < NN) {
            float a = ab2[o], cc = ab2[CC + o];
            size_t p = (size_t)b*NN + n;
            float z = (a >= 0.f) ? wsmax[p*CC + o] : wsmin[p*CC + o];
            v = fmaf(a, z, cc);
            v = v > 0.f ? v : 0.f;
        }
        t[o*65 + nl] = v;
    }
    __syncthreads();
#pragma unroll
    for (int i = 0; i < 32; ++i) {
        int idx = i*256 + tid;
        int o = idx >> 6, nl = idx & 63;
        int n = n0 + nl;
        if (n < NN) out[((size_t)b*CC + o)*NN + n] = t[o*65 + nl];
    }
}

extern "C" void kernel_launch(void* const* d_in, const int* in_sizes, int n_in,
                              void* d_out, int out_size, void* d_ws, size_t ws_size,
                              hipStream_t stream) {
    const float* x      = (const float*)d_in[0];
    const float* coords = (const float*)d_in[1];
    const float* w1     = (const float*)d_in[2];
    const float* g1     = (const float*)d_in[3];
    const float* b1     = (const float*)d_in[4];
    const float* w2     = (const float*)d_in[5];
    const float* g2     = (const float*)d_in[6];
    const float* b2     = (const float*)d_in[7];
    float* out = (float*)d_out;

    char* ws = (char*)d_ws;
    size_t off = 0;
    int* knn_idx = (int*)(ws + off);   off += (size_t)ROWS * sizeof(int);        // 3.32 MB
    float* stats = (float*)(ws + off); off += 1024 * sizeof(float);
    float* gsum2 = stats + 256, *gsq2 = stats + 384;
    float* ab1   = stats + 512;
    float* ab2   = stats + 768;
    __half* feats = (__half*)(ws + off); off += (size_t)BB*NN*DD * sizeof(__half); // 3.32 MB
    __half* w1h   = (__half*)(ws + off); off += CC*CC * sizeof(__half);
    __half* w2h   = (__half*)(ws + off); off += CC*CC * sizeof(__half);
    float* wsmax = (float*)(ws + off);  off += (size_t)PAIRS*CC * sizeof(float);  // 13.3 MB
    float* wsmin = (float*)(ws + off);  off += (size_t)PAIRS*CC * sizeof(float);  // 13.3 MB
    int*   cnt   = (int*)(ws + off);    off += (size_t)PAIRS * sizeof(int);       // 104 KB
    float* Mfin  = (float*)(ws + off);  off += (size_t)MSTRIDE * sizeof(float);   // 50 KB
    // aliases (dead before k_fused writes wsmax/wsmin):
    float* s_arr = wsmax;                    // PAIRS*64 fp32 = 6.64 MB  (<13.3)
    float* Mpart = wsmin;                    // 128*12416 fp32 = 6.36 MB (<13.3)
    (void)ws_size; (void)in_sizes; (void)n_in; (void)out_size;

    hipMemsetAsync(stats, 0, 512 * sizeof(float), stream);
    hipMemsetAsync(cnt, 0, (size_t)PAIRS * sizeof(int), stream);

    dim3 gT((NN + 63)/64, BB);
    k_prep_feats<<<gT, 256, 0, stream>>>(x, feats);
    k_convert_w<<<64, 256, 0, stream>>>(w1, w2, w1h, w2h);
    k_knn<<<PAIRS, 64, 0, stream>>>(coords, knn_idx, cnt);
    k_gather_sum<<<PAIRS/4, 256, 0, stream>>>(feats, knn_idx, s_arr);
    k_gram<<<GRAM_BLOCKS, 256, 0, stream>>>(feats, s_arr, cnt, Mpart);
    k_gram_reduce<<<(MSTRIDE + 255)/256, 256, 0, stream>>>(Mpart, Mfin);
    k_stats1<<<CC, 256, 0, stream>>>(Mfin, w1h, g1, b1, ab1);
    k_fused_mfma<<<GRID_MM, 256, 0, stream>>>(feats, knn_idx, w1h, w2h, ab1,
                                              gsum2, gsq2, wsmax, wsmin);
    k_finalize<<<1, CC, 0, stream>>>(gsum2, gsq2, g2, b2, ab2);
    dim3 gE((NN + 63)/64, BB);
    k_epilogue<<<gE, 256, 0, stream>>>(wsmax, wsmin, ab2, out);
}